// Round 11
// baseline (528.773 us; speedup 1.0000x reference)
//
#include <hip/hip_runtime.h>

#define OUT_W 320
#define OUT_H 240
#define NPIX (OUT_W * OUT_H)
#define S_IN 128
#define SLICE (S_IN * S_IN)
#define VOLC (S_IN * S_IN * S_IN)
#define ZSEG 8                  // waves per block, each owns 32 z-samples
#define NBLK (NPIX / 64)        // 1200 blocks
#define CPX  (NBLK / 8)         // 150 blocks per XCD (1200 % 8 == 0 -> bijective)

// One block = 64 pixels x 8 z-segment waves. Slice schedule is EXACT:
// k(z) = (z-1)>>1, so the z-loop is a static unrolled pipeline of
// {16-tap gather, 2 composite steps}. ALL code is macro-expanded inline:
// rounds 5/8 showed ~500MB scratch traffic (VGPR=40, VALUBusy 5%) because
// the [&]-capturing bilin/step lambdas were NOT inlined at 50 call sites,
// forcing captured state to memory. Macros leave zero call boundaries.
// (Macro params renamed KK_/ZI_/KI_ -- round 9's param `z` collided with
// the float4 member access `.z` during preprocessing.)

#define BILIN(KK_, S) do { const float* p_ = vol + (KK_) * SLICE;                                      \
    (S).x = w00*p_[o00]          + w01*p_[o01]          + w10*p_[o10]          + w11*p_[o11];          \
    (S).y = w00*p_[o00+VOLC]     + w01*p_[o01+VOLC]     + w10*p_[o10+VOLC]     + w11*p_[o11+VOLC];     \
    (S).z = w00*p_[o00+2*VOLC]   + w01*p_[o01+2*VOLC]   + w10*p_[o10+2*VOLC]   + w11*p_[o11+2*VOLC];   \
    (S).w = w00*p_[o00+3*VOLC]   + w01*p_[o01+3*VOLC]   + w10*p_[o10+3*VOLC]   + w11*p_[o11+3*VOLC];   \
  } while (0)

#define ZERO4(S) do { (S).x = 0.f; (S).y = 0.f; (S).z = 0.f; (S).w = 0.f; } while (0)

// one composite step at output z-index ZI_ using slices KI_ (S0) and KI_+1 (S1).
// edge taps carry zeroed DATA, so no weight mask is needed.
#define STEP(ZI_, KI_, S0, S1) do {                                      \
    float wz1_ = (float)(ZI_) * (128.0f/255.0f) - 0.5f - (float)(KI_);   \
    float wz0_ = 1.0f - wz1_;                                            \
    float r_  = wz0_*(S0).x + wz1_*(S1).x;                               \
    float g_  = wz0_*(S0).y + wz1_*(S1).y;                               \
    float b_  = wz0_*(S0).z + wz1_*(S1).z;                               \
    float dv_ = wz0_*(S0).w + wz1_*(S1).w;                               \
    float d_  = dv_ * (100.0f/256.0f);  /* DENSITY_FACTOR/RAY_SAMPLES */ \
    T *= (1.0f - d_);                   /* inclusive cumprod */          \
    float w_ = d_ * T;                                                   \
    wsum += w_; a0 += w_*r_; a1 += w_*g_; a2 += w_*b_;                   \
  } while (0)

__global__ __launch_bounds__(512, 6) void raycast_kernel(const float* __restrict__ vol,
                                                         float* __restrict__ out) {
    const int lane = threadIdx.x & 63;
    const int seg  = threadIdx.x >> 6;                               // 0..7
    const int o    = (blockIdx.x & 7) * CPX + (blockIdx.x >> 3);     // XCD-contiguous index
    const int pix  = o * 64 + lane;
    const int x = pix % OUT_W;
    const int y = pix / OUT_W;   // uniform within block

    // ---- bilinear (y,x) setup: grid_sample align_corners=False, zero padding ----
    float fx = (float)x * (128.0f / 319.0f) - 0.5f;
    int   ix0 = (int)floorf(fx);
    float wx1 = fx - (float)ix0;
    float wx0 = 1.0f - wx1;
    float wxa = (ix0 >= 0)       ? wx0 : 0.0f;
    float wxb = (ix0 + 1 < S_IN) ? wx1 : 0.0f;
    int   cx0 = max(ix0, 0);
    int   cx1 = min(ix0 + 1, S_IN - 1);

    float fy = (float)y * (128.0f / 239.0f) - 0.5f;
    int   iy0 = (int)floorf(fy);
    float wy1 = fy - (float)iy0;
    float wy0 = 1.0f - wy1;
    float wya = (iy0 >= 0)       ? wy0 : 0.0f;
    float wyb = (iy0 + 1 < S_IN) ? wy1 : 0.0f;
    int   cy0 = max(iy0, 0);
    int   cy1 = min(iy0 + 1, S_IN - 1);

    const float w00 = wya * wxa, w01 = wya * wxb, w10 = wyb * wxa, w11 = wyb * wxb;
    const int o00 = cy0 * S_IN + cx0;
    const int o01 = cy0 * S_IN + cx1;
    const int o10 = cy1 * S_IN + cx0;
    const int o11 = cy1 * S_IN + cx1;

    float T = 1.f, wsum = 0.f, a0 = 0.f, a1 = 0.f, a2 = 0.f;

    // ---- z-segment: z in [32*seg, 32*seg+32), slices 16*seg-1 .. 16*seg+16 ----
    const int m0 = 16 * seg - 1;
    const int zb = 32 * seg;
    float4 A, B, C;
    if (m0 >= 0) BILIN(m0, A); else ZERO4(A);     // zero-pad below volume (seg 0)
    BILIN(m0 + 1, B);

    STEP(zb, m0, A, B);                           // lone even step (mate in prev segment)
#pragma unroll
    for (int j = 0; j < 15; ++j) {                // slices m0+2+j <= 127 always valid
        BILIN(m0 + 2 + j, C);
        STEP(zb + 1 + 2 * j, m0 + 1 + j, B, C);
        STEP(zb + 2 + 2 * j, m0 + 1 + j, B, C);
        B = C;
    }
    if (16 * seg + 16 < S_IN) BILIN(16 * seg + 16, C); else ZERO4(C);  // pad above (seg 7)
    STEP(zb + 31, 16 * seg + 15, B, C);           // lone odd step (mate in next segment)

    // ---- combine 8 segments per pixel (associative composition) ----
    __shared__ float shT[ZSEG][64], shW[ZSEG][64], sh0[ZSEG][64], sh1[ZSEG][64], sh2[ZSEG][64];
    shT[seg][lane] = T;
    shW[seg][lane] = wsum;
    sh0[seg][lane] = a0;
    sh1[seg][lane] = a1;
    sh2[seg][lane] = a2;
    __syncthreads();

    if (threadIdx.x < 64) {
        float Tg = 1.f, ws = 0.f, r0 = 0.f, r1 = 0.f, r2 = 0.f;
#pragma unroll
        for (int s = 0; s < ZSEG; ++s) {
            r0 += Tg * sh0[s][lane];
            r1 += Tg * sh1[s][lane];
            r2 += Tg * sh2[s][lane];
            ws += Tg * shW[s][lane];
            Tg *= shT[s][lane];
        }
        float alpha = 1.0f - Tg;
        float inv   = alpha / (ws + 1e-8f);
        out[0 * NPIX + pix] = r0 * inv;
        out[1 * NPIX + pix] = r1 * inv;
        out[2 * NPIX + pix] = r2 * inv;
        out[3 * NPIX + pix] = alpha;
    }
}

extern "C" void kernel_launch(void* const* d_in, const int* in_sizes, int n_in,
                              void* d_out, int out_size, void* d_ws, size_t ws_size,
                              hipStream_t stream) {
    (void)in_sizes; (void)n_in; (void)out_size; (void)d_ws; (void)ws_size;
    const float* vol = (const float*)d_in[0];
    float* out = (float*)d_out;
    raycast_kernel<<<NBLK, 512, 0, stream>>>(vol, out);
}

// Round 12
// 232.543 us; speedup vs baseline: 2.2739x; 2.2739x over previous
//
#include <hip/hip_runtime.h>

#define OUT_W 320
#define OUT_H 240
#define NPIX (OUT_W * OUT_H)
#define S_IN 128
#define SLICE (S_IN * S_IN)
#define VOLC (S_IN * S_IN * S_IN)
#define ZSEG 8                  // waves per block, each owns 32 z-samples
#define NBLK (NPIX / 64)        // 1200 blocks
#define CPX  (NBLK / 8)         // 150 blocks per XCD (1200 % 8 == 0 -> bijective)

// One block = 64 pixels x 8 z-segment waves. Slice schedule is EXACT:
// k(z) = (z-1)>>1, so the z-loop is a static unrolled pipeline of
// {16-tap gather, 2 composite steps}.
// LESSON (rounds 5/8/11): __launch_bounds__(512, 6) was interpreted as a
// 12-waves/EU constraint -> VGPR cap 40 -> ~500MB spill traffic, VALUBusy 5%.
// All three "scratch" kernels showed VGPR_Count=40 == 512/12.8 exactly.
// Fix: NO min-occupancy arg; let the allocator keep the pipeline in registers.

#define BILIN(KK_, S) do { const float* p_ = vol + (KK_) * SLICE;                                      \
    (S).x = w00*p_[o00]          + w01*p_[o01]          + w10*p_[o10]          + w11*p_[o11];          \
    (S).y = w00*p_[o00+VOLC]     + w01*p_[o01+VOLC]     + w10*p_[o10+VOLC]     + w11*p_[o11+VOLC];     \
    (S).z = w00*p_[o00+2*VOLC]   + w01*p_[o01+2*VOLC]   + w10*p_[o10+2*VOLC]   + w11*p_[o11+2*VOLC];   \
    (S).w = w00*p_[o00+3*VOLC]   + w01*p_[o01+3*VOLC]   + w10*p_[o10+3*VOLC]   + w11*p_[o11+3*VOLC];   \
  } while (0)

#define ZERO4(S) do { (S).x = 0.f; (S).y = 0.f; (S).z = 0.f; (S).w = 0.f; } while (0)

// one composite step at output z-index ZI_ using slices KI_ (S0) and KI_+1 (S1).
// edge taps carry zeroed DATA, so no weight mask is needed.
#define STEP(ZI_, KI_, S0, S1) do {                                      \
    float wz1_ = (float)(ZI_) * (128.0f/255.0f) - 0.5f - (float)(KI_);   \
    float wz0_ = 1.0f - wz1_;                                            \
    float r_  = wz0_*(S0).x + wz1_*(S1).x;                               \
    float g_  = wz0_*(S0).y + wz1_*(S1).y;                               \
    float b_  = wz0_*(S0).z + wz1_*(S1).z;                               \
    float dv_ = wz0_*(S0).w + wz1_*(S1).w;                               \
    float d_  = dv_ * (100.0f/256.0f);  /* DENSITY_FACTOR/RAY_SAMPLES */ \
    T *= (1.0f - d_);                   /* inclusive cumprod */          \
    float w_ = d_ * T;                                                   \
    wsum += w_; a0 += w_*r_; a1 += w_*g_; a2 += w_*b_;                   \
  } while (0)

__global__ __launch_bounds__(512) void raycast_kernel(const float* __restrict__ vol,
                                                      float* __restrict__ out) {
    const int lane = threadIdx.x & 63;
    const int seg  = threadIdx.x >> 6;                               // 0..7
    const int o    = (blockIdx.x & 7) * CPX + (blockIdx.x >> 3);     // XCD-contiguous index
    const int pix  = o * 64 + lane;
    const int x = pix % OUT_W;
    const int y = pix / OUT_W;   // uniform within block

    // ---- bilinear (y,x) setup: grid_sample align_corners=False, zero padding ----
    float fx = (float)x * (128.0f / 319.0f) - 0.5f;
    int   ix0 = (int)floorf(fx);
    float wx1 = fx - (float)ix0;
    float wx0 = 1.0f - wx1;
    float wxa = (ix0 >= 0)       ? wx0 : 0.0f;
    float wxb = (ix0 + 1 < S_IN) ? wx1 : 0.0f;
    int   cx0 = max(ix0, 0);
    int   cx1 = min(ix0 + 1, S_IN - 1);

    float fy = (float)y * (128.0f / 239.0f) - 0.5f;
    int   iy0 = (int)floorf(fy);
    float wy1 = fy - (float)iy0;
    float wy0 = 1.0f - wy1;
    float wya = (iy0 >= 0)       ? wy0 : 0.0f;
    float wyb = (iy0 + 1 < S_IN) ? wy1 : 0.0f;
    int   cy0 = max(iy0, 0);
    int   cy1 = min(iy0 + 1, S_IN - 1);

    const float w00 = wya * wxa, w01 = wya * wxb, w10 = wyb * wxa, w11 = wyb * wxb;
    const int o00 = cy0 * S_IN + cx0;
    const int o01 = cy0 * S_IN + cx1;
    const int o10 = cy1 * S_IN + cx0;
    const int o11 = cy1 * S_IN + cx1;

    float T = 1.f, wsum = 0.f, a0 = 0.f, a1 = 0.f, a2 = 0.f;

    // ---- z-segment: z in [32*seg, 32*seg+32), slices 16*seg-1 .. 16*seg+16 ----
    const int m0 = 16 * seg - 1;
    const int zb = 32 * seg;
    float4 A, B, C;
    if (m0 >= 0) BILIN(m0, A); else ZERO4(A);     // zero-pad below volume (seg 0)
    BILIN(m0 + 1, B);

    STEP(zb, m0, A, B);                           // lone even step (mate in prev segment)
#pragma unroll
    for (int j = 0; j < 15; ++j) {                // slices m0+2+j <= 127 always valid
        BILIN(m0 + 2 + j, C);
        STEP(zb + 1 + 2 * j, m0 + 1 + j, B, C);
        STEP(zb + 2 + 2 * j, m0 + 1 + j, B, C);
        B = C;
    }
    if (16 * seg + 16 < S_IN) BILIN(16 * seg + 16, C); else ZERO4(C);  // pad above (seg 7)
    STEP(zb + 31, 16 * seg + 15, B, C);           // lone odd step (mate in next segment)

    // ---- combine 8 segments per pixel (associative composition) ----
    __shared__ float shT[ZSEG][64], shW[ZSEG][64], sh0[ZSEG][64], sh1[ZSEG][64], sh2[ZSEG][64];
    shT[seg][lane] = T;
    shW[seg][lane] = wsum;
    sh0[seg][lane] = a0;
    sh1[seg][lane] = a1;
    sh2[seg][lane] = a2;
    __syncthreads();

    if (threadIdx.x < 64) {
        float Tg = 1.f, ws = 0.f, r0 = 0.f, r1 = 0.f, r2 = 0.f;
#pragma unroll
        for (int s = 0; s < ZSEG; ++s) {
            r0 += Tg * sh0[s][lane];
            r1 += Tg * sh1[s][lane];
            r2 += Tg * sh2[s][lane];
            ws += Tg * shW[s][lane];
            Tg *= shT[s][lane];
        }
        float alpha = 1.0f - Tg;
        float inv   = alpha / (ws + 1e-8f);
        out[0 * NPIX + pix] = r0 * inv;
        out[1 * NPIX + pix] = r1 * inv;
        out[2 * NPIX + pix] = r2 * inv;
        out[3 * NPIX + pix] = alpha;
    }
}

extern "C" void kernel_launch(void* const* d_in, const int* in_sizes, int n_in,
                              void* d_out, int out_size, void* d_ws, size_t ws_size,
                              hipStream_t stream) {
    (void)in_sizes; (void)n_in; (void)out_size; (void)d_ws; (void)ws_size;
    const float* vol = (const float*)d_in[0];
    float* out = (float*)d_out;
    raycast_kernel<<<NBLK, 512, 0, stream>>>(vol, out);
}